// Round 9
// baseline (161.503 us; speedup 1.0000x reference)
//
#include <hip/hip_runtime.h>

// EdgeConv with KNN graph: B=8, N=4096, D=3, E=64, K=32.
// R8 post-mortem: neither pipe saturated; time ~= LDS + VALU sum (dependency
// serialization at 16 waves/CU). Dominant term: sweep ds_read_b128 (64/pt).
// This version shares candidate loads across TWO points per sweep:
//  - wave processes points A,B: each plane b128 read feeds 8 distances
//    (4 cands x 2 pts) via packed FMA -> 32 LDS reads/pt (halved).
//  - u16 truncated keys (monotone => pool SUPERSET of exact top-32, R6
//    proof), pkA[32]+pkB[32] in regs under (512,4) 128 budget.
//  - packed u16 minima bitonic ONCE (pair 0) seeds thresholds for both
//    points; pair 1 carries converged H (R6-proven ~1 probe).
//  - ballot probes, index-only compaction, exact-fp32 partial bitonic
//    (lower-index tie-break == jax.lax.top_k), readlane epilogue: unchanged.
// SPILL DISCIPLINE (R2/R3): every loop touching pkA/pkB FULLY unrolled;
// tripwire = FETCH_SIZE explosion.

#define NPTS 4096
#define KNN  32

#define WFENCE() __asm__ volatile("s_waitcnt lgkmcnt(0)" ::: "memory")

typedef unsigned short u16x2 __attribute__((ext_vector_type(2)));
typedef float          f32x2 __attribute__((ext_vector_type(2)));

__device__ __forceinline__ unsigned lane_prefix(unsigned long long m) {
    return __builtin_amdgcn_mbcnt_hi((unsigned)(m >> 32),
           __builtin_amdgcn_mbcnt_lo((unsigned)m, 0u));
}
__device__ __forceinline__ unsigned pk_min_u16(unsigned a, unsigned b) {
    return __builtin_bit_cast(unsigned, __builtin_elementwise_min(
        __builtin_bit_cast(u16x2, a), __builtin_bit_cast(u16x2, b)));
}
__device__ __forceinline__ unsigned pk_max_u16(unsigned a, unsigned b) {
    return __builtin_bit_cast(unsigned, __builtin_elementwise_max(
        __builtin_bit_cast(u16x2, a), __builtin_bit_cast(u16x2, b)));
}
// lo16 = top16(d0), hi16 = top16(d1)
__device__ __forceinline__ unsigned pack_keys(float d0, float d1) {
    return __builtin_amdgcn_perm(__builtin_bit_cast(unsigned, d1),
                                 __builtin_bit_cast(unsigned, d0), 0x07060302u);
}

__global__ __launch_bounds__(512, 4)
void edgeconv_knn_kernel(const float* __restrict__ x,
                         const float* __restrict__ theta_w,
                         const float* __restrict__ theta_b,
                         const float* __restrict__ phi_w,
                         const float* __restrict__ phi_b,
                         float* __restrict__ out)
{
    __shared__ float    s_x[NPTS];         // 16 KB per plane
    __shared__ float    s_y[NPTS];
    __shared__ float    s_z[NPTS];
    __shared__ float    s_sq[NPTS];
    __shared__ unsigned s_pool[8][64];     // 2 KB: per-wave survivor indices

    const int tid  = threadIdx.x;
    const int wv   = tid >> 6;
    const int lane = tid & 63;

    const int b  = blockIdx.x >> 7;        // 128 WGs per batch
    const int i0 = (blockIdx.x & 127) << 5;// 32 points per WG (4 per wave)

    // lane == output channel e
    const float tw0 = theta_w[lane];
    const float tw1 = theta_w[64 + lane];
    const float tw2 = theta_w[128 + lane];
    const float tbv = theta_b[lane];
    const float pw0 = phi_w[lane];
    const float pw1 = phi_w[64 + lane];
    const float pw2 = phi_w[128 + lane];
    const float pbv = phi_b[lane];

    const float* xb = x + (size_t)b * NPTS * 3;
    for (int p = tid; p < NPTS; p += 512) {
        const float px = xb[p * 3 + 0];
        const float py = xb[p * 3 + 1];
        const float pz = xb[p * 3 + 2];
        s_x[p] = px; s_y[p] = py; s_z[p] = pz;
        s_sq[p] = fmaf(pz, pz, fmaf(py, py, px * px));
    }
    __syncthreads();

    unsigned HA = 0u, HB = 0u;             // carried u16 thresholds

    for (int pr = 0; pr < 2; ++pr) {
        const int iA = i0 + wv * 4 + pr * 2;
        const int iB = iA + 1;
        const float pxA = s_x[iA], pyA = s_y[iA], pzA = s_z[iA], sqA = s_sq[iA];
        const float pxB = s_x[iB], pyB = s_y[iB], pzB = s_z[iB], sqB = s_sq[iB];
        const f32x2 PXA = {pxA, pxA}, PYA = {pyA, pyA}, PZA = {pzA, pzA}, SQA = {sqA, sqA};
        const f32x2 PXB = {pxB, pxB}, PYB = {pyB, pyB}, PZB = {pzB, pzB}, SQB = {sqB, sqB};
        const f32x2 N2  = {-2.0f, -2.0f};
        const f32x2 Z02 = {0.0f, 0.0f};

        // ---- shared sweep: lane owns candidates j = 256*t + 4*lane + {0..3} ----
        // slot s=0..63 -> j = ((s>>2)<<8) + (lane<<2) + (s&3)
        unsigned pkA[32], pkB[32];
        unsigned pminA = 0xFFFFFFFFu, pminB = 0xFFFFFFFFu;
        #pragma unroll
        for (int t = 0; t < 16; ++t) {
            const int jb = (t << 8) + (lane << 2);
            const float4 QX = *(const float4*)&s_x[jb];
            const float4 QY = *(const float4*)&s_y[jb];
            const float4 QZ = *(const float4*)&s_z[jb];
            const float4 QS = *(const float4*)&s_sq[jb];
            const f32x2 X0 = {QX.x, QX.y}, X1 = {QX.z, QX.w};
            const f32x2 Y0 = {QY.x, QY.y}, Y1 = {QY.z, QY.w};
            const f32x2 Zc0 = {QZ.x, QZ.y}, Zc1 = {QZ.z, QZ.w};
            const f32x2 S0 = {QS.x, QS.y}, S1 = {QS.z, QS.w};
            // point A
            const f32x2 dtA0 = __builtin_elementwise_fma(PZA, Zc0,
                               __builtin_elementwise_fma(PYA, Y0, PXA * X0));
            const f32x2 dtA1 = __builtin_elementwise_fma(PZA, Zc1,
                               __builtin_elementwise_fma(PYA, Y1, PXA * X1));
            f32x2 dA0 = __builtin_elementwise_fma(N2, dtA0, SQA + S0);
            f32x2 dA1 = __builtin_elementwise_fma(N2, dtA1, SQA + S1);
            dA0 = __builtin_elementwise_max(dA0, Z02);
            dA1 = __builtin_elementwise_max(dA1, Z02);
            pkA[2 * t]     = pack_keys(dA0.x, dA0.y);
            pkA[2 * t + 1] = pack_keys(dA1.x, dA1.y);
            pminA = pk_min_u16(pminA, pkA[2 * t]);
            pminA = pk_min_u16(pminA, pkA[2 * t + 1]);
            // point B (loads shared)
            const f32x2 dtB0 = __builtin_elementwise_fma(PZB, Zc0,
                               __builtin_elementwise_fma(PYB, Y0, PXB * X0));
            const f32x2 dtB1 = __builtin_elementwise_fma(PZB, Zc1,
                               __builtin_elementwise_fma(PYB, Y1, PXB * X1));
            f32x2 dB0 = __builtin_elementwise_fma(N2, dtB0, SQB + S0);
            f32x2 dB1 = __builtin_elementwise_fma(N2, dtB1, SQB + S1);
            dB0 = __builtin_elementwise_max(dB0, Z02);
            dB1 = __builtin_elementwise_max(dB1, Z02);
            pkB[2 * t]     = pack_keys(dB0.x, dB0.y);
            pkB[2 * t + 1] = pack_keys(dB1.x, dB1.y);
            pminB = pk_min_u16(pminB, pkB[2 * t]);
            pminB = pk_min_u16(pminB, pkB[2 * t + 1]);
        }

        if (pr == 0) {
            // packed minima bitonic: lo16 tracks A, hi16 tracks B
            const unsigned mnA = min(pminA & 0xFFFFu, pminA >> 16);
            const unsigned mnB = min(pminB & 0xFFFFu, pminB >> 16);
            unsigned v = mnA | (mnB << 16);
            #pragma unroll
            for (int k = 2; k <= 64; k <<= 1) {
                #pragma unroll
                for (int jj = k >> 1; jj >= 1; jj >>= 1) {
                    const unsigned o  = (unsigned)__shfl_xor((int)v, jj, 64);
                    const unsigned mn = pk_min_u16(v, o);
                    const unsigned mx = pk_max_u16(v, o);
                    const bool wantmin = (((lane & k) == 0) == ((lane & jj) == 0));
                    v = wantmin ? mn : mx;
                }
            }
            const unsigned v32 = (unsigned)__builtin_amdgcn_readlane((int)v, 32);
            HA = v32 & 0xFFFFu;            // 33rd-smallest lane-min, point A
            HB = v32 >> 16;                // point B
        }

        #pragma unroll
        for (int half = 0; half < 2; ++half) {
            const bool isB = (half == 1);
            const float px = isB ? pxB : pxA, py = isB ? pyB : pyA;
            const float pz = isB ? pzB : pzA, sqi = isB ? sqB : sqA;
            const int   iX = isB ? iB : iA;

            auto cnt_lt = [&](unsigned T) -> unsigned {
                unsigned c = 0;
                #pragma unroll
                for (int k2 = 0; k2 < 32; ++k2) {
                    const unsigned pv = isB ? pkB[k2] : pkA[k2];
                    c += (unsigned)__popcll(__ballot((pv & 0xFFFFu) < T));
                    c += (unsigned)__popcll(__ballot((pv >> 16)     < T));
                }
                return c;
            };

            // ---- threshold search in u16 key space (carried seed) ----
            unsigned H = isB ? HB : HA;
            unsigned L = 0u;
            unsigned c = cnt_lt(H);
            if (c < KNN) {                 // raise by octaves (exp LSB = 0x80)
                unsigned step = 0x80u;
                do {
                    unsigned Hn = H + step;
                    if (Hn > 0xFFFFu) Hn = 0xFFFFu;
                    L = H; H = Hn; step <<= 1;
                    c = cnt_lt(H);
                } while (c < KNN);
            }
            while (c > 64u && (H - L) > 1u) {
                const unsigned M  = L + ((H - L) >> 1);
                const unsigned cm = cnt_lt(M);
                if (cm >= KNN) { H = M; c = cm; } else { L = M; }
            }
            if (isB) HB = H; else HA = H;  // carry to next pair

            // ---- compaction: survivor indices only (ballot + mbcnt) ----
            WFENCE();                      // prior pool consumers done
            unsigned base = 0;
            #pragma unroll
            for (int s = 0; s < 64; ++s) {
                const unsigned pv = isB ? pkB[s >> 1] : pkA[s >> 1];
                const unsigned kk = (s & 1) ? (pv >> 16) : (pv & 0xFFFFu);
                const bool pred = kk < H;
                const unsigned long long bm = __ballot(pred);
                if (bm) {
                    if (pred) {
                        const unsigned pos = base + lane_prefix(bm);
                        if (pos < 64u)
                            s_pool[wv][pos] =
                                (unsigned)(((s >> 2) << 8) + (lane << 2) + (s & 3));
                    }
                    base += (unsigned)__popcll(bm);
                }
            }
            WFENCE();
            const unsigned m = base < 64u ? base : 64u;   // m >= 32 guaranteed

            // ---- exact fp32 keys for pool members (identical op chain) ----
            unsigned myk = 0xFFFFFFFFu;
            unsigned myj = 0u;             // sentinel, never selected (m>=32)
            if ((unsigned)lane < m) {
                myj = s_pool[wv][lane];
                const float qx = s_x[myj], qy = s_y[myj], qz = s_z[myj];
                const float sqj = s_sq[myj];
                const float dt = fmaf(pz, qz, fmaf(py, qy, px * qx));
                float d = fmaf(-2.0f, dt, sqi + sqj);
                d = fmaxf(d, 0.0f);
                myk = __builtin_bit_cast(unsigned, d);
            }

            // ---- partial bitonic: 32-sorts + one merge -> bottom-32 ----
            #pragma unroll
            for (int k = 2; k <= 32; k <<= 1) {
                #pragma unroll
                for (int jj = k >> 1; jj >= 1; jj >>= 1) {
                    const unsigned ok = (unsigned)__shfl_xor((int)myk, jj, 64);
                    const unsigned oj = (unsigned)__shfl_xor((int)myj, jj, 64);
                    const bool wantmin = (((lane & k) == 0) == ((lane & jj) == 0));
                    const bool less = (myk < ok) || (myk == ok && myj < oj);
                    if (less != wantmin) { myk = ok; myj = oj; }
                }
            }
            {   // k=64, jj=32: lanes 0..31 <- the 32 smallest (unordered)
                const unsigned ok = (unsigned)__shfl_xor((int)myk, 32, 64);
                const unsigned oj = (unsigned)__shfl_xor((int)myj, 32, 64);
                const bool wantmin = ((lane & 32) == 0);
                const bool less = (myk < ok) || (myk == ok && myj < oj);
                if (less != wantmin) { myk = ok; myj = oj; }
            }

            // ---- epilogue: lane = channel e; max over the 32 selected ----
            float dx = 0.f, dy = 0.f, dz = 0.f;
            if (lane < KNN) {
                dx = s_x[myj] - px; dy = s_y[myj] - py; dz = s_z[myj] - pz;
            }
            const float basev = tbv + pbv + fmaf(pw2, pz, fmaf(pw1, py, pw0 * px));
            float mx = -3.0e38f;
            #pragma unroll
            for (int t = 0; t < KNN; ++t) {
                const float ndx = __builtin_bit_cast(float, __builtin_amdgcn_readlane(__builtin_bit_cast(int, dx), t));
                const float ndy = __builtin_bit_cast(float, __builtin_amdgcn_readlane(__builtin_bit_cast(int, dy), t));
                const float ndz = __builtin_bit_cast(float, __builtin_amdgcn_readlane(__builtin_bit_cast(int, dz), t));
                const float proj = fmaf(tw2, ndz, fmaf(tw1, ndy, tw0 * ndx));
                mx = fmaxf(mx, proj);
            }
            out[(((size_t)b * NPTS + (size_t)iX) << 6) + lane] = mx + basev;
        }
    }
}

extern "C" void kernel_launch(void* const* d_in, const int* in_sizes, int n_in,
                              void* d_out, int out_size, void* d_ws, size_t ws_size,
                              hipStream_t stream) {
    const float* x  = (const float*)d_in[0];
    const float* tw = (const float*)d_in[1];
    const float* tb = (const float*)d_in[2];
    const float* pw = (const float*)d_in[3];
    const float* pb = (const float*)d_in[4];
    float* out = (float*)d_out;

    dim3 grid(8 * (NPTS / 32));   // 1024 WGs: 128 per batch, 32 points each
    dim3 block(512);
    hipLaunchKernelGGL(edgeconv_knn_kernel, grid, block, 0, stream,
                       x, tw, tb, pw, pb, out);
}

// Round 10
// 139.531 us; speedup vs baseline: 1.1575x; 1.1575x over previous
//
#include <hip/hip_runtime.h>

// EdgeConv with KNN graph: B=8, N=4096, D=3, E=64, K=32.
// R9 post-mortem: key-array REGISTER footprint is the binding constraint
// (64-reg key block -> AGPR parking -> churn), not LDS read count. R8
// (pk[32], 1 pt/sweep) is the reference structure.
// This round: break the 16-waves/CU LDS cap. Planes x,y,z only (48KB+2KB
// pool = 50KB -> 3 blocks/CU = 24 waves); sq_j recomputed in-sweep with the
// BIT-IDENTICAL packed fmaf chain (sq = fma(z,z,fma(y,y,x*x))) => identical
// distances, self-dist exactly 0, u16 keys unchanged => selection identical.
// (512,6) -> 85-VGPR budget; peak live ~75 (pk[32] + 12 load regs + temps).
// R7's spill came from scalar chains + 4 planes at this budget; this is the
// packed 3-plane variant. TRIPWIRE: FETCH>4MB => spill => revert (512,4).
// Everything else R8-proven: u16 monotone-truncation superset pool, sampled
// threshold (minima bitonic), ballot probes, index-only compaction, exact
// fp32 partial bitonic (lower-index tie-break == jax.lax.top_k), readlane
// epilogue. SPILL DISCIPLINE: every loop touching pk[] FULLY unrolled.

#define NPTS 4096
#define KNN  32

#define WFENCE() __asm__ volatile("s_waitcnt lgkmcnt(0)" ::: "memory")

typedef unsigned short u16x2 __attribute__((ext_vector_type(2)));
typedef float          f32x2 __attribute__((ext_vector_type(2)));

__device__ __forceinline__ unsigned lane_prefix(unsigned long long m) {
    return __builtin_amdgcn_mbcnt_hi((unsigned)(m >> 32),
           __builtin_amdgcn_mbcnt_lo((unsigned)m, 0u));
}
__device__ __forceinline__ unsigned pk_min_u16(unsigned a, unsigned b) {
    return __builtin_bit_cast(unsigned, __builtin_elementwise_min(
        __builtin_bit_cast(u16x2, a), __builtin_bit_cast(u16x2, b)));
}
// lo16 = top16(d0), hi16 = top16(d1)
__device__ __forceinline__ unsigned pack_keys(float d0, float d1) {
    return __builtin_amdgcn_perm(__builtin_bit_cast(unsigned, d1),
                                 __builtin_bit_cast(unsigned, d0), 0x07060302u);
}

__global__ __launch_bounds__(512, 6)
void edgeconv_knn_kernel(const float* __restrict__ x,
                         const float* __restrict__ theta_w,
                         const float* __restrict__ theta_b,
                         const float* __restrict__ phi_w,
                         const float* __restrict__ phi_b,
                         float* __restrict__ out)
{
    __shared__ float    s_x[NPTS];         // 16 KB per plane (48 KB total)
    __shared__ float    s_y[NPTS];
    __shared__ float    s_z[NPTS];
    __shared__ unsigned s_pool[8][64];     // 2 KB: per-wave survivor indices

    const int tid  = threadIdx.x;
    const int wv   = tid >> 6;
    const int lane = tid & 63;

    const int b  = blockIdx.x >> 7;        // 128 WGs per batch
    const int i0 = (blockIdx.x & 127) << 5;// 32 points per WG (4 per wave)

    // lane == output channel e
    const float tw0 = theta_w[lane];
    const float tw1 = theta_w[64 + lane];
    const float tw2 = theta_w[128 + lane];
    const float tbv = theta_b[lane];
    const float pw0 = phi_w[lane];
    const float pw1 = phi_w[64 + lane];
    const float pw2 = phi_w[128 + lane];
    const float pbv = phi_b[lane];

    const float* xb = x + (size_t)b * NPTS * 3;
    for (int p = tid; p < NPTS; p += 512) {
        s_x[p] = xb[p * 3 + 0];
        s_y[p] = xb[p * 3 + 1];
        s_z[p] = xb[p * 3 + 2];
    }
    __syncthreads();

    for (int r = 0; r < 4; ++r) {
        const int i = i0 + wv * 4 + r;
        const float px = s_x[i], py = s_y[i], pz = s_z[i];
        const float sqi = fmaf(pz, pz, fmaf(py, py, px * px));
        const f32x2 PX2 = {px, px}, PY2 = {py, py}, PZ2 = {pz, pz};
        const f32x2 SQI2 = {sqi, sqi};
        const f32x2 N2   = {-2.0f, -2.0f};
        const f32x2 Z02  = {0.0f, 0.0f};

        // ---- sweep: lane owns candidates j = 256*t + 4*lane + {0..3} ----
        // slot s=0..63 -> j = ((s>>2)<<8) + (lane<<2) + (s&3)
        unsigned pk[32];
        unsigned pmin = 0xFFFFFFFFu;
        #pragma unroll
        for (int t = 0; t < 16; ++t) {
            const int jb = (t << 8) + (lane << 2);
            const float4 QX = *(const float4*)&s_x[jb];
            const float4 QY = *(const float4*)&s_y[jb];
            const float4 QZ = *(const float4*)&s_z[jb];
            const f32x2 X0 = {QX.x, QX.y}, X1 = {QX.z, QX.w};
            const f32x2 Y0 = {QY.x, QY.y}, Y1 = {QY.z, QY.w};
            const f32x2 Zc0 = {QZ.x, QZ.y}, Zc1 = {QZ.z, QZ.w};
            // sq_j with the identical chain: fma(z,z, fma(y,y, x*x))
            const f32x2 S0 = __builtin_elementwise_fma(Zc0, Zc0,
                             __builtin_elementwise_fma(Y0, Y0, X0 * X0));
            const f32x2 S1 = __builtin_elementwise_fma(Zc1, Zc1,
                             __builtin_elementwise_fma(Y1, Y1, X1 * X1));
            // dot with the identical chain: fma(pz,qz, fma(py,qy, px*qx))
            const f32x2 dt0 = __builtin_elementwise_fma(PZ2, Zc0,
                              __builtin_elementwise_fma(PY2, Y0, PX2 * X0));
            const f32x2 dt1 = __builtin_elementwise_fma(PZ2, Zc1,
                              __builtin_elementwise_fma(PY2, Y1, PX2 * X1));
            f32x2 d0 = __builtin_elementwise_fma(N2, dt0, SQI2 + S0);
            f32x2 d1 = __builtin_elementwise_fma(N2, dt1, SQI2 + S1);
            d0 = __builtin_elementwise_max(d0, Z02);
            d1 = __builtin_elementwise_max(d1, Z02);
            pk[2 * t]     = pack_keys(d0.x, d0.y);
            pk[2 * t + 1] = pack_keys(d1.x, d1.y);
            pmin = pk_min_u16(pmin, pk[2 * t]);
            pmin = pk_min_u16(pmin, pk[2 * t + 1]);
        }
        unsigned mn = min(pmin & 0xFFFFu, pmin >> 16);   // per-lane min (u16)

        // ---- bitonic sort of 64 lane-minima -> sampled threshold ----
        #pragma unroll
        for (int k = 2; k <= 64; k <<= 1) {
            #pragma unroll
            for (int jj = k >> 1; jj >= 1; jj >>= 1) {
                const unsigned o = (unsigned)__shfl_xor((int)mn, jj, 64);
                const bool wantmin = (((lane & k) == 0) == ((lane & jj) == 0));
                const bool less = (mn < o);
                if (less != wantmin) mn = o;
            }
        }
        unsigned H = (unsigned)__builtin_amdgcn_readlane((int)mn, 32);

        // wave-uniform count of u16 keys strictly below T (ballot -> scalar)
        auto cnt_lt = [&](unsigned T) -> unsigned {
            unsigned c = 0;
            #pragma unroll
            for (int k2 = 0; k2 < 32; ++k2) {
                c += (unsigned)__popcll(__ballot((pk[k2] & 0xFFFFu) < T));
                c += (unsigned)__popcll(__ballot((pk[k2] >> 16)     < T));
            }
            return c;
        };

        // ---- threshold search in u16 key space ----
        unsigned L = 0u;
        unsigned c = cnt_lt(H);
        if (c < KNN) {                       // raise by octaves (exp LSB = 0x80)
            unsigned step = 0x80u;
            do {
                unsigned Hn = H + step;
                if (Hn > 0xFFFFu) Hn = 0xFFFFu;
                L = H; H = Hn; step <<= 1;
                c = cnt_lt(H);
            } while (c < KNN);
        }
        while (c > 64u && (H - L) > 1u) {
            const unsigned M  = L + ((H - L) >> 1);
            const unsigned cm = cnt_lt(M);
            if (cm >= KNN) { H = M; c = cm; } else { L = M; }
        }

        // ---- compaction: survivor indices only (ballot + mbcnt) ----
        WFENCE();                            // prior pool consumers done
        unsigned base = 0;
        #pragma unroll
        for (int s = 0; s < 64; ++s) {
            const unsigned kk = (s & 1) ? (pk[s >> 1] >> 16)
                                        : (pk[s >> 1] & 0xFFFFu);
            const bool pred = kk < H;
            const unsigned long long bm = __ballot(pred);
            if (bm) {
                if (pred) {
                    const unsigned pos = base + lane_prefix(bm);
                    if (pos < 64u)
                        s_pool[wv][pos] =
                            (unsigned)(((s >> 2) << 8) + (lane << 2) + (s & 3));
                }
                base += (unsigned)__popcll(bm);
            }
        }
        WFENCE();
        const unsigned m = base < 64u ? base : 64u;   // m >= 32 guaranteed

        // ---- exact fp32 keys for pool members (identical op chain) ----
        unsigned myk = 0xFFFFFFFFu;
        unsigned myj = 0u;                   // sentinel, never selected (m>=32)
        if ((unsigned)lane < m) {
            myj = s_pool[wv][lane];
            const float qx = s_x[myj], qy = s_y[myj], qz = s_z[myj];
            const float sqj = fmaf(qz, qz, fmaf(qy, qy, qx * qx));
            const float dt  = fmaf(pz, qz, fmaf(py, qy, px * qx));
            float d = fmaf(-2.0f, dt, sqi + sqj);
            d = fmaxf(d, 0.0f);
            myk = __builtin_bit_cast(unsigned, d);
        }

        // ---- partial bitonic: 32-sorts + one merge -> bottom-32 unordered ----
        #pragma unroll
        for (int k = 2; k <= 32; k <<= 1) {
            #pragma unroll
            for (int jj = k >> 1; jj >= 1; jj >>= 1) {
                const unsigned ok = (unsigned)__shfl_xor((int)myk, jj, 64);
                const unsigned oj = (unsigned)__shfl_xor((int)myj, jj, 64);
                const bool wantmin = (((lane & k) == 0) == ((lane & jj) == 0));
                const bool less = (myk < ok) || (myk == ok && myj < oj);
                if (less != wantmin) { myk = ok; myj = oj; }
            }
        }
        {   // k=64, jj=32: lanes 0..31 <- the 32 smallest (unordered)
            const unsigned ok = (unsigned)__shfl_xor((int)myk, 32, 64);
            const unsigned oj = (unsigned)__shfl_xor((int)myj, 32, 64);
            const bool wantmin = ((lane & 32) == 0);
            const bool less = (myk < ok) || (myk == ok && myj < oj);
            if (less != wantmin) { myk = ok; myj = oj; }
        }

        // ---- epilogue: lane = channel e; max over the 32 selected ----
        float dx = 0.f, dy = 0.f, dz = 0.f;
        if (lane < KNN) {
            dx = s_x[myj] - px; dy = s_y[myj] - py; dz = s_z[myj] - pz;
        }
        const float basev = tbv + pbv + fmaf(pw2, pz, fmaf(pw1, py, pw0 * px));
        float mx = -3.0e38f;
        #pragma unroll
        for (int t = 0; t < KNN; ++t) {
            const float ndx = __builtin_bit_cast(float, __builtin_amdgcn_readlane(__builtin_bit_cast(int, dx), t));
            const float ndy = __builtin_bit_cast(float, __builtin_amdgcn_readlane(__builtin_bit_cast(int, dy), t));
            const float ndz = __builtin_bit_cast(float, __builtin_amdgcn_readlane(__builtin_bit_cast(int, dz), t));
            const float proj = fmaf(tw2, ndz, fmaf(tw1, ndy, tw0 * ndx));
            mx = fmaxf(mx, proj);
        }
        out[(((size_t)b * NPTS + (size_t)i) << 6) + lane] = mx + basev;
    }
}

extern "C" void kernel_launch(void* const* d_in, const int* in_sizes, int n_in,
                              void* d_out, int out_size, void* d_ws, size_t ws_size,
                              hipStream_t stream) {
    const float* x  = (const float*)d_in[0];
    const float* tw = (const float*)d_in[1];
    const float* tb = (const float*)d_in[2];
    const float* pw = (const float*)d_in[3];
    const float* pb = (const float*)d_in[4];
    float* out = (float*)d_out;

    dim3 grid(8 * (NPTS / 32));   // 1024 WGs: 128 per batch, 32 points each
    dim3 block(512);
    hipLaunchKernelGGL(edgeconv_knn_kernel, grid, block, 0, stream,
                       x, tw, tb, pw, pb, out);
}